// Round 7
// baseline (140.095 us; speedup 1.0000x reference)
//
#include <hip/hip_runtime.h>
#include <math.h>

#define NT 16
#define NR 25
#define DZ 512
#define D2Z 1024
#define NC 64

typedef short bf16x8 __attribute__((ext_vector_type(8)));
typedef float f32x4  __attribute__((ext_vector_type(4)));

#define TP  76    // convW LDS tile pitch (ushorts)
#define XSP 520   // x LDS pitch (ushorts): 1040B rows, 16B-aligned
#define CP  68    // C tile pitch (floats)

static __device__ inline unsigned short f2bf(float v) {
    union { float f; unsigned u; } x; x.f = v;
    unsigned r = x.u + 0x7fffu + ((x.u >> 16) & 1u);
    return (unsigned short)(r >> 16);
}
static __device__ inline float bf2f(unsigned short h) {
    union { float f; unsigned u; } x; x.u = ((unsigned)h) << 16; return x.f;
}

// ---------------------------------------------------------------------------
// k_prep: blocks 0..383 convW transpose+split, 384..783 distances.
// XCD-ALIGNED remap (R7): jt = vb%16 (was vb/24) so the block that WRITES
// j-tile jt runs on XCD jt%8 — the same XCD whose k_fused blocks (bid%8 =
// jt%8) will READ it. W1h/W1l lines then sit in the reader's own L2
// (~1.6 MB/XCD, fits 4 MB) instead of requiring cross-XCD dirty-line snoops
// (R2 evidence: 68 µs k_fused with only 6.9 MB HBM FETCH).
// ---------------------------------------------------------------------------
__global__ __launch_bounds__(256) void k_prep(
    const float* __restrict__ x, const float* __restrict__ W1,
    unsigned short* __restrict__ W1h, unsigned short* __restrict__ W1l,
    float* __restrict__ Dm)
{
    __shared__ unsigned short th[64 * TP], tl[64 * TP];
    int vb = blockIdx.x;
    int tid = threadIdx.x;

    if (vb < 384) {
        int jt = vb & 15;            // j-tile -> XCD = vb%8 = jt%8 (reader-aligned)
        int rs = vb >> 4;            // r-slice 0..23
        int r0 = rs * 64;
        int j0 = jt * 64;
        int c  = r0 >> 9;
        int rb = r0 & 511;

        #pragma unroll
        for (int it = 0; it < 4; it++) {
            int rl = (tid >> 4) + it * 16;
            int jj = (tid & 15) * 4;
            float4 v = *(const float4*)(W1 + (size_t)(r0 + rl) * D2Z + j0 + jj);
            unsigned short h0 = f2bf(v.x), h1 = f2bf(v.y), h2 = f2bf(v.z), h3 = f2bf(v.w);
            th[rl * TP + jj + 0] = h0; tl[rl * TP + jj + 0] = f2bf(v.x - bf2f(h0));
            th[rl * TP + jj + 1] = h1; tl[rl * TP + jj + 1] = f2bf(v.y - bf2f(h1));
            th[rl * TP + jj + 2] = h2; tl[rl * TP + jj + 2] = f2bf(v.z - bf2f(h2));
            th[rl * TP + jj + 3] = h3; tl[rl * TP + jj + 3] = f2bf(v.w - bf2f(h3));
        }
        __syncthreads();

        #pragma unroll
        for (int it = 0; it < 4; it++) {
            int jl = (tid >> 4) + it * 16;
            int r4 = (tid & 15) * 4;
            ushort4 hv = make_ushort4(th[(r4+0)*TP + jl], th[(r4+1)*TP + jl],
                                      th[(r4+2)*TP + jl], th[(r4+3)*TP + jl]);
            ushort4 lv = make_ushort4(tl[(r4+0)*TP + jl], tl[(r4+1)*TP + jl],
                                      tl[(r4+2)*TP + jl], tl[(r4+3)*TP + jl]);
            size_t dst = ((size_t)c * D2Z + j0 + jl) * DZ + rb + r4;
            *(ushort4*)(W1h + dst) = hv;
            *(ushort4*)(W1l + dst) = lv;
        }
    } else {
        int i = vb - 384;
        int k = i & 15, a = i >> 4;
        int lane = tid & 63;
        int w    = tid >> 6;
        const float* xk = x + (size_t)k * NR * DZ;

        const float4* xap = (const float4*)(xk + a * DZ);
        float4 a0 = xap[lane];
        float4 a1 = xap[lane + 64];

        float sa = a0.x*a0.x + a0.y*a0.y + a0.z*a0.z + a0.w*a0.w
                 + a1.x*a1.x + a1.y*a1.y + a1.z*a1.z + a1.w*a1.w;
        #pragma unroll
        for (int off = 32; off; off >>= 1) sa += __shfl_xor(sa, off);
        float inva = 1.0f / sqrtf(sa);
        a0.x *= inva; a0.y *= inva; a0.z *= inva; a0.w *= inva;
        a1.x *= inva; a1.y *= inva; a1.z *= inva; a1.w *= inva;
        float sqa = a0.x*a0.x + a0.y*a0.y + a0.z*a0.z + a0.w*a0.w
                  + a1.x*a1.x + a1.y*a1.y + a1.z*a1.z + a1.w*a1.w;
        #pragma unroll
        for (int off = 32; off; off >>= 1) sqa += __shfl_xor(sqa, off);

        for (int j = w; j < NR; j += 4) {
            const float4* xjp = (const float4*)(xk + j * DZ);
            float4 j0 = xjp[lane];
            float4 j1 = xjp[lane + 64];
            float sj = j0.x*j0.x + j0.y*j0.y + j0.z*j0.z + j0.w*j0.w
                     + j1.x*j1.x + j1.y*j1.y + j1.z*j1.z + j1.w*j1.w;
            #pragma unroll
            for (int off = 32; off; off >>= 1) sj += __shfl_xor(sj, off);
            float invj = 1.0f / sqrtf(sj);
            j0.x *= invj; j0.y *= invj; j0.z *= invj; j0.w *= invj;
            j1.x *= invj; j1.y *= invj; j1.z *= invj; j1.w *= invj;

            float sqj = j0.x*j0.x + j0.y*j0.y + j0.z*j0.z + j0.w*j0.w
                      + j1.x*j1.x + j1.y*j1.y + j1.z*j1.z + j1.w*j1.w;
            float dij = a0.x*j0.x + a0.y*j0.y + a0.z*j0.z + a0.w*j0.w
                      + a1.x*j1.x + a1.y*j1.y + a1.z*j1.z + a1.w*j1.w;
            #pragma unroll
            for (int off = 32; off; off >>= 1) {
                sqj += __shfl_xor(sqj, off);
                dij += __shfl_xor(dij, off);
            }
            float d2 = sqa + sqj - 2.0f * dij;
            float d  = sqrtf(fmaxf(d2, 0.0f));
            if (lane == 0) Dm[((size_t)k * NR + a) * NR + j] = d;
        }
    }
}

// ---------------------------------------------------------------------------
// k_fused (R6-verified): 1024 threads, 16 waves = 4 col-groups x 4 K-quarters,
// partials in Ct[4]. W reads now hit the local XCD L2 (k_prep alignment).
// ---------------------------------------------------------------------------
__global__ __launch_bounds__(1024) void k_fused(
    const float* __restrict__ x,
    const unsigned short* __restrict__ W1h, const unsigned short* __restrict__ W1l,
    const float* __restrict__ b1, const float* __restrict__ Dm,
    float* __restrict__ G, float* __restrict__ cnt)
{
    __shared__ unsigned short xs_h[25 * XSP], xs_l[25 * XSP];   // 26 KB each
    __shared__ float Ct[4][75 * CP];                            // 81.6 KB
    __shared__ float Dm_s[NR * NR];
    __shared__ float red[16][64];
    __shared__ float cred[4];

    int bid = blockIdx.x;
    int k  = bid >> 4;          // task
    int jt = bid & 15;          // j-tile -> XCD = jt%8 (matches k_prep writer)
    int j0 = jt * 64;

    int tid  = threadIdx.x;
    int lane = tid & 63;
    int w    = tid >> 6;        // 0..15
    int g    = w & 3;           // col group (16 cols each)
    int kh   = w >> 2;          // K quarter (kc 4*kh .. 4*kh+3)
    int q    = lane >> 4;
    int ln16 = lane & 15;

    for (int idx = tid; idx < NR * NR; idx += 1024)
        Dm_s[idx] = Dm[(size_t)k * NR * NR + idx];

    // ---- stage x once (bit-identical hi/lo split) ----
    for (int gi = tid; gi < NR * 64; gi += 1024) {
        int row = gi >> 6;
        int c8  = (gi & 63) * 8;
        const float* xp = x + ((size_t)k * NR + row) * DZ + c8;
        float4 v0 = *(const float4*)(xp);
        float4 v1 = *(const float4*)(xp + 4);
        unsigned short h;
        ushort4 ha, hb, la, lb;
        h = f2bf(v0.x); ha.x = h; la.x = f2bf(v0.x - bf2f(h));
        h = f2bf(v0.y); ha.y = h; la.y = f2bf(v0.y - bf2f(h));
        h = f2bf(v0.z); ha.z = h; la.z = f2bf(v0.z - bf2f(h));
        h = f2bf(v0.w); ha.w = h; la.w = f2bf(v0.w - bf2f(h));
        h = f2bf(v1.x); hb.x = h; lb.x = f2bf(v1.x - bf2f(h));
        h = f2bf(v1.y); hb.y = h; lb.y = f2bf(v1.y - bf2f(h));
        h = f2bf(v1.z); hb.z = h; lb.z = f2bf(v1.z - bf2f(h));
        h = f2bf(v1.w); hb.w = h; lb.w = f2bf(v1.w - bf2f(h));
        *(ushort4*)&xs_h[row * XSP + c8]     = ha;
        *(ushort4*)&xs_h[row * XSP + c8 + 4] = hb;
        *(ushort4*)&xs_l[row * XSP + c8]     = la;
        *(ushort4*)&xs_l[row * XSP + c8 + 4] = lb;
    }
    __syncthreads();

    // semihard count (jt==0, waves 0..3 only; verified body)
    if (jt == 0 && tid < 256) {
        float cntv = 0.0f;
        for (int idx = tid; idx < 2000; idx += 256) {
            int a   = idx / 80;
            int rem = idx - a * 80;
            int mi  = rem / 20;
            int nn  = rem - mi * 20;
            int qa = a % 5, mdiv = a / 5;
            int m = mi + (mi >= mdiv);
            int p = qa + 5 * m;
            int ng = nn >> 2, o = nn & 3;
            int n = ng * 5 + o + (o >= qa);
            float tm = Dm_s[a * NR + n] - Dm_s[a * NR + p];
            cntv += ((tm > 0.0f) && (tm <= 0.8f)) ? 1.0f : 0.0f;
        }
        #pragma unroll
        for (int off = 32; off; off >>= 1) cntv += __shfl_xor(cntv, off);
        if (lane == 0) cred[w] = cntv;
    }

    int rowA1 = 16 + ln16;
    if (rowA1 > 24) rowA1 = 24;    // pad lanes duplicate row 24 (rows 25..31 unused)

    const unsigned short* wb_h = W1h + ((size_t)j0 + g * 16 + ln16) * DZ + q * 8;
    const unsigned short* wb_l = W1l + ((size_t)j0 + g * 16 + ln16) * DZ + q * 8;

    for (int c = 0; c < 3; c++) {
        f32x4 acc0 = (f32x4){0.f,0.f,0.f,0.f};
        f32x4 acc1 = (f32x4){0.f,0.f,0.f,0.f};
        const unsigned short* wch = wb_h + (size_t)c * D2Z * DZ;
        const unsigned short* wcl = wb_l + (size_t)c * D2Z * DZ;

        #pragma unroll
        for (int kc2 = 0; kc2 < 4; kc2++) {     // this wave's K quarter
            int kc  = kh * 4 + kc2;
            int kog = kc * 32 + q * 8;
            bf16x8 b_h = *(const bf16x8*)(wch + kc * 32);
            bf16x8 b_l = *(const bf16x8*)(wcl + kc * 32);
            bf16x8 a0h = *(const bf16x8*)&xs_h[ln16 * XSP + kog];
            bf16x8 a0l = *(const bf16x8*)&xs_l[ln16 * XSP + kog];
            bf16x8 a1h = *(const bf16x8*)&xs_h[rowA1 * XSP + kog];
            bf16x8 a1l = *(const bf16x8*)&xs_l[rowA1 * XSP + kog];
            acc0 = __builtin_amdgcn_mfma_f32_16x16x32_bf16(a0h, b_h, acc0, 0, 0, 0);
            acc0 = __builtin_amdgcn_mfma_f32_16x16x32_bf16(a0h, b_l, acc0, 0, 0, 0);
            acc0 = __builtin_amdgcn_mfma_f32_16x16x32_bf16(a0l, b_h, acc0, 0, 0, 0);
            acc1 = __builtin_amdgcn_mfma_f32_16x16x32_bf16(a1h, b_h, acc1, 0, 0, 0);
            acc1 = __builtin_amdgcn_mfma_f32_16x16x32_bf16(a1h, b_l, acc1, 0, 0, 0);
            acc1 = __builtin_amdgcn_mfma_f32_16x16x32_bf16(a1l, b_h, acc1, 0, 0, 0);
        }

        int col = g * 16 + ln16;
        #pragma unroll
        for (int r = 0; r < 4; r++) {
            int r0 = q * 4 + r;
            Ct[kh][(c * 25 + r0) * CP + col] = acc0[r];
            int r1 = 16 + q * 4 + r;
            if (r1 < 25) Ct[kh][(c * 25 + r1) * CP + col] = acc1[r];
        }
    }
    __syncthreads();

    if (jt == 0 && tid == 0)
        cnt[k] = cred[0] + cred[1] + cred[2] + cred[3];

    // ---- accum: thread = (col j, valid-m index h, a-split ag 4-way) ----
    int j  = tid & 63;
    int h  = (tid >> 6) & 3;
    int ag = tid >> 8;          // 0..3, wave-uniform
    float b1v = b1[j0 + j];

    float a3v[NR];
    #pragma unroll
    for (int i = 0; i < NR; i++)
        a3v[i] = Ct[0][(50 + i) * CP + j] + Ct[1][(50 + i) * CP + j]
               + Ct[2][(50 + i) * CP + j] + Ct[3][(50 + i) * CP + j];

    float acc = 0.0f;
    #define ACC_BODY(a) { \
        const int qa = (a) % 5, mdiv = (a) / 5; \
        int m = h + (h >= mdiv); \
        int p = qa + 5 * m; \
        float a1v = Ct[0][(a) * CP + j] + Ct[1][(a) * CP + j] \
                  + Ct[2][(a) * CP + j] + Ct[3][(a) * CP + j]; \
        float a2v = Ct[0][(25 + p) * CP + j] + Ct[1][(25 + p) * CP + j] \
                  + Ct[2][(25 + p) * CP + j] + Ct[3][(25 + p) * CP + j]; \
        float dap = Dm_s[(a) * NR + p]; \
        float s = a1v + a2v + b1v; \
        _Pragma("unroll") \
        for (int ng = 0; ng < 5; ng++) { \
            _Pragma("unroll") \
            for (int o = 0; o < 4; o++) { \
                int n = ng * 5 + o + (o >= qa); \
                float tm = Dm_s[(a) * NR + n] - dap; \
                bool sel = (tm > 0.0f) && (tm <= 0.8f); \
                float pre = fmaxf(s + a3v[n], 0.0f); \
                acc = fmaf(sel ? 1.0f : 0.0f, pre, acc); \
            } \
        } }
    if (ag == 0) {
        #pragma unroll
        for (int a = 0; a < 7; a++) ACC_BODY(a)
    } else if (ag == 1) {
        #pragma unroll
        for (int a = 7; a < 13; a++) ACC_BODY(a)
    } else if (ag == 2) {
        #pragma unroll
        for (int a = 13; a < 19; a++) ACC_BODY(a)
    } else {
        #pragma unroll
        for (int a = 19; a < 25; a++) ACC_BODY(a)
    }
    #undef ACC_BODY

    red[tid >> 6][j] = acc;
    __syncthreads();
    if (tid < 64) {
        float s = 0.0f;
        #pragma unroll
        for (int r = 0; r < 16; r++) s += red[r][tid];
        G[(size_t)k * D2Z + j0 + tid] = s;
    }
}

// ---------------------------------------------------------------------------
// Tail (R6-verified): task-batched, 128 blocks each. kA's block decode swapped
// to jq = bid&15 so its G reads align with k_fused's writers (XCD = jq%8).
// ---------------------------------------------------------------------------

// kA: pooled partials. grid 128 = (jq 0..15) x (ct 0..7), 64-j slices.
__global__ __launch_bounds__(256) void kA(const float* __restrict__ G,
                                          const float* __restrict__ W2,
                                          float* __restrict__ pp)
{
    __shared__ float GsT[64 * 16];      // [jj][t], 4 KB
    __shared__ float red2[4][16][64];   // 16 KB
    int jq = blockIdx.x & 15, ct = blockIdx.x >> 4;   // XCD = jq%8 = G-writer XCD
    int tid = threadIdx.x;

    for (int idx = tid; idx < 1024; idx += 256) {
        int t = idx & 15, jj = idx >> 4;
        GsT[jj * 16 + t] = G[(size_t)t * D2Z + jq * 64 + jj];
    }
    __syncthreads();

    int cg = tid & 63, sub = tid >> 6;
    int col = ct * 64 + cg;
    float acc[16];
    #pragma unroll
    for (int t = 0; t < 16; t++) acc[t] = 0.0f;

    for (int jj = 0; jj < 16; jj++) {
        int jr = sub * 16 + jj;
        float wv = W2[(size_t)(jq * 64 + jr) * DZ + col];
        const float4* gp = (const float4*)&GsT[jr * 16];
        float4 g0 = gp[0], g1 = gp[1], g2 = gp[2], g3 = gp[3];
        acc[0]  = fmaf(g0.x, wv, acc[0]);  acc[1]  = fmaf(g0.y, wv, acc[1]);
        acc[2]  = fmaf(g0.z, wv, acc[2]);  acc[3]  = fmaf(g0.w, wv, acc[3]);
        acc[4]  = fmaf(g1.x, wv, acc[4]);  acc[5]  = fmaf(g1.y, wv, acc[5]);
        acc[6]  = fmaf(g1.z, wv, acc[6]);  acc[7]  = fmaf(g1.w, wv, acc[7]);
        acc[8]  = fmaf(g2.x, wv, acc[8]);  acc[9]  = fmaf(g2.y, wv, acc[9]);
        acc[10] = fmaf(g2.z, wv, acc[10]); acc[11] = fmaf(g2.w, wv, acc[11]);
        acc[12] = fmaf(g3.x, wv, acc[12]); acc[13] = fmaf(g3.y, wv, acc[13]);
        acc[14] = fmaf(g3.z, wv, acc[14]); acc[15] = fmaf(g3.w, wv, acc[15]);
    }
    #pragma unroll
    for (int t = 0; t < 16; t++) red2[sub][t][cg] = acc[t];
    __syncthreads();
    for (int r = 0; r < 4; r++) {
        int oi = tid + r * 256;
        int t = oi >> 6, c2 = oi & 63;
        float s = red2[0][t][c2] + red2[1][t][c2] + red2[2][t][c2] + red2[3][t][c2];
        pp[(size_t)jq * 8192 + t * DZ + ct * 64 + c2] = s;
    }
}

// kB: pooled finish (16 slices + cnt*b2) then u partials.
// grid 128 = (ct 0..15) x (cq 0..7), 64-c slices.
__global__ __launch_bounds__(256) void kB(const float* __restrict__ pp,
                                          const float* __restrict__ cnt,
                                          const float* __restrict__ b2,
                                          const float* __restrict__ W3,
                                          float* __restrict__ up)
{
    __shared__ float PsT[64 * 16];      // [cl][t], 4 KB
    __shared__ float red2[4][16][64];
    int ct = blockIdx.x & 15, cq = blockIdx.x >> 4;
    int tid = threadIdx.x;

    for (int idx = tid; idx < 1024; idx += 256) {
        int t = idx & 15, cl = idx >> 4;
        int c = cq * 64 + cl;
        float v = cnt[t] * b2[c];
        #pragma unroll
        for (int sl = 0; sl < 16; sl++)
            v += pp[(size_t)sl * 8192 + t * DZ + c];
        PsT[cl * 16 + t] = v;
    }
    __syncthreads();

    int cg = tid & 63, sub = tid >> 6;
    int col = ct * 64 + cg;
    float acc[16];
    #pragma unroll
    for (int t = 0; t < 16; t++) acc[t] = 0.0f;

    for (int cl = 0; cl < 16; cl++) {
        int cr = sub * 16 + cl;
        float wv = W3[(size_t)(cq * 64 + cr) * D2Z + col];
        const float4* gp = (const float4*)&PsT[cr * 16];
        float4 g0 = gp[0], g1 = gp[1], g2 = gp[2], g3 = gp[3];
        acc[0]  = fmaf(g0.x, wv, acc[0]);  acc[1]  = fmaf(g0.y, wv, acc[1]);
        acc[2]  = fmaf(g0.z, wv, acc[2]);  acc[3]  = fmaf(g0.w, wv, acc[3]);
        acc[4]  = fmaf(g1.x, wv, acc[4]);  acc[5]  = fmaf(g1.y, wv, acc[5]);
        acc[6]  = fmaf(g1.z, wv, acc[6]);  acc[7]  = fmaf(g1.w, wv, acc[7]);
        acc[8]  = fmaf(g2.x, wv, acc[8]);  acc[9]  = fmaf(g2.y, wv, acc[9]);
        acc[10] = fmaf(g2.z, wv, acc[10]); acc[11] = fmaf(g2.w, wv, acc[11]);
        acc[12] = fmaf(g3.x, wv, acc[12]); acc[13] = fmaf(g3.y, wv, acc[13]);
        acc[14] = fmaf(g3.z, wv, acc[14]); acc[15] = fmaf(g3.w, wv, acc[15]);
    }
    #pragma unroll
    for (int t = 0; t < 16; t++) red2[sub][t][cg] = acc[t];
    __syncthreads();
    for (int r = 0; r < 4; r++) {
        int oi = tid + r * 256;
        int t = oi >> 6, c2 = oi & 63;
        float s = red2[0][t][c2] + red2[1][t][c2] + red2[2][t][c2] + red2[3][t][c2];
        up[(size_t)cq * 16384 + t * D2Z + ct * 64 + c2] = s;
    }
}

// kC: u finish (8 slices + b3, relu) then o partials.
// grid 128 = (ct 0..7) x (sq 0..15), 64-s slices.
__global__ __launch_bounds__(256) void kC(const float* __restrict__ up,
                                          const float* __restrict__ b3,
                                          const float* __restrict__ W4,
                                          float* __restrict__ op)
{
    __shared__ float UsT[64 * 16];      // [sl][t], 4 KB
    __shared__ float red2[4][16][64];
    int ct = blockIdx.x & 7, sq = blockIdx.x >> 3;
    int tid = threadIdx.x;

    for (int idx = tid; idx < 1024; idx += 256) {
        int t = idx & 15, sl = idx >> 4;
        int s = sq * 64 + sl;
        float v = b3[s];
        #pragma unroll
        for (int c8 = 0; c8 < 8; c8++)
            v += up[(size_t)c8 * 16384 + t * D2Z + s];
        UsT[sl * 16 + t] = fmaxf(v, 0.0f);
    }
    __syncthreads();

    int cg = tid & 63, sub = tid >> 6;
    int col = ct * 64 + cg;
    float acc[16];
    #pragma unroll
    for (int t = 0; t < 16; t++) acc[t] = 0.0f;

    for (int sl = 0; sl < 16; sl++) {
        int sr = sub * 16 + sl;
        float wv = W4[(size_t)(sq * 64 + sr) * DZ + col];
        const float4* gp = (const float4*)&UsT[sr * 16];
        float4 g0 = gp[0], g1 = gp[1], g2 = gp[2], g3 = gp[3];
        acc[0]  = fmaf(g0.x, wv, acc[0]);  acc[1]  = fmaf(g0.y, wv, acc[1]);
        acc[2]  = fmaf(g0.z, wv, acc[2]);  acc[3]  = fmaf(g0.w, wv, acc[3]);
        acc[4]  = fmaf(g1.x, wv, acc[4]);  acc[5]  = fmaf(g1.y, wv, acc[5]);
        acc[6]  = fmaf(g1.z, wv, acc[6]);  acc[7]  = fmaf(g1.w, wv, acc[7]);
        acc[8]  = fmaf(g2.x, wv, acc[8]);  acc[9]  = fmaf(g2.y, wv, acc[9]);
        acc[10] = fmaf(g2.z, wv, acc[10]); acc[11] = fmaf(g2.w, wv, acc[11]);
        acc[12] = fmaf(g3.x, wv, acc[12]); acc[13] = fmaf(g3.y, wv, acc[13]);
        acc[14] = fmaf(g3.z, wv, acc[14]); acc[15] = fmaf(g3.w, wv, acc[15]);
    }
    #pragma unroll
    for (int t = 0; t < 16; t++) red2[sub][t][cg] = acc[t];
    __syncthreads();
    for (int r = 0; r < 4; r++) {
        int oi = tid + r * 256;
        int t = oi >> 6, c2 = oi & 63;
        float s = red2[0][t][c2] + red2[1][t][c2] + red2[2][t][c2] + red2[3][t][c2];
        op[(size_t)sq * 8192 + t * DZ + ct * 64 + c2] = s;
    }
}

// kD: o finish (16 slices + b4), score, softmax. grid 16 (one per task).
__global__ __launch_bounds__(256) void kD(const float* __restrict__ op,
                                          const float* __restrict__ b4,
                                          const float* __restrict__ Wc,
                                          const float* __restrict__ bc,
                                          float* __restrict__ out)
{
    __shared__ float Os[DZ];
    __shared__ float tmp[4][64];
    int k = blockIdx.x;
    int tid = threadIdx.x;

    for (int c = tid; c < DZ; c += 256) {
        float v = b4[c];
        #pragma unroll
        for (int sl = 0; sl < 16; sl++)
            v += op[(size_t)sl * 8192 + k * DZ + c];
        Os[c] = v;
    }
    __syncthreads();

    int oc = tid & 63, seg = tid >> 6;
    float a0 = 0.f, a1 = 0.f, a2 = 0.f, a3 = 0.f;
    int r0 = seg * 128;
    #pragma unroll 4
    for (int rr = r0; rr < r0 + 128; rr += 4) {
        a0 = fmaf(Os[rr+0], Wc[(size_t)(rr+0) * NC + oc], a0);
        a1 = fmaf(Os[rr+1], Wc[(size_t)(rr+1) * NC + oc], a1);
        a2 = fmaf(Os[rr+2], Wc[(size_t)(rr+2) * NC + oc], a2);
        a3 = fmaf(Os[rr+3], Wc[(size_t)(rr+3) * NC + oc], a3);
    }
    tmp[seg][oc] = (a0 + a1) + (a2 + a3);
    __syncthreads();
    if (tid < 64) {
        float sc = bc[tid] + tmp[0][tid] + tmp[1][tid] + tmp[2][tid] + tmp[3][tid];
        float m = sc;
        #pragma unroll
        for (int off = 32; off; off >>= 1) m = fmaxf(m, __shfl_xor(m, off));
        float e = expf(sc - m);
        float ss = e;
        #pragma unroll
        for (int off = 32; off; off >>= 1) ss += __shfl_xor(ss, off);
        out[k * NC + tid] = e / ss;
    }
}

extern "C" void kernel_launch(void* const* d_in, const int* in_sizes, int n_in,
                              void* d_out, int out_size, void* d_ws, size_t ws_size,
                              hipStream_t stream)
{
    const float* x  = (const float*)d_in[0];
    const float* W1 = (const float*)d_in[1];
    const float* b1 = (const float*)d_in[2];
    const float* W2 = (const float*)d_in[3];
    const float* b2 = (const float*)d_in[4];
    const float* W3 = (const float*)d_in[5];
    const float* b3 = (const float*)d_in[6];
    const float* W4 = (const float*)d_in[7];
    const float* b4 = (const float*)d_in[8];
    const float* Wc = (const float*)d_in[9];
    const float* bc = (const float*)d_in[10];
    float* out = (float*)d_out;

    float* ws   = (float*)d_ws;
    float* Dm   = ws;                         // 10000
    float* cnt  = ws + 10016;                 // 16
    float* G    = ws + 10032;                 // 16384 -> end 26416
    float* pp   = ws + 26416;                 // 16*16*512  = 131072 -> 157488
    float* up   = ws + 157488;                // 8*16*1024  = 131072 -> 288560
    float* op   = ws + 288560;                // 16*16*512  = 131072 -> 419632
    unsigned short* W1h = (unsigned short*)(ws + 419632);
    unsigned short* W1l = W1h + 3 * D2Z * DZ;

    k_prep <<<784,  256, 0, stream>>>(x, W1, W1h, W1l, Dm);
    k_fused<<<256, 1024, 0, stream>>>(x, W1h, W1l, b1, Dm, G, cnt);
    kA     <<<128,  256, 0, stream>>>(G, W2, pp);
    kB     <<<128,  256, 0, stream>>>(pp, cnt, b2, W3, up);
    kC     <<<128,  256, 0, stream>>>(up, b3, W4, op);
    kD     <<<NT,   256, 0, stream>>>(op, b4, Wc, bc, out);
}

// Round 9
// 133.218 us; speedup vs baseline: 1.0516x; 1.0516x over previous
//
#include <hip/hip_runtime.h>
#include <math.h>

#define NT 16
#define NR 25
#define DZ 512
#define D2Z 1024
#define NC 64

typedef short bf16x8 __attribute__((ext_vector_type(8)));
typedef float f32x4  __attribute__((ext_vector_type(4)));

#define XSP 520   // x LDS pitch (ushorts): 1040B rows, 16B-aligned
#define CP  68    // C tile pitch (floats)

static __device__ inline unsigned short f2bf(float v) {
    union { float f; unsigned u; } x; x.f = v;
    unsigned r = x.u + 0x7fffu + ((x.u >> 16) & 1u);
    return (unsigned short)(r >> 16);
}
static __device__ inline float bf2f(unsigned short h) {
    union { float f; unsigned u; } x; x.u = ((unsigned)h) << 16; return x.f;
}

// ---------------------------------------------------------------------------
// k_dist (R0-verified distance body, now standalone): 400 blocks = 16 tasks x
// 25 anchors. The W transpose kernel is GONE — k_fused reads W1 directly.
// ---------------------------------------------------------------------------
__global__ __launch_bounds__(256) void k_dist(
    const float* __restrict__ x, float* __restrict__ Dm)
{
    int i = blockIdx.x;
    int tid = threadIdx.x;
    int k = i & 15, a = i >> 4;
    int lane = tid & 63;
    int w    = tid >> 6;
    const float* xk = x + (size_t)k * NR * DZ;

    const float4* xap = (const float4*)(xk + a * DZ);
    float4 a0 = xap[lane];
    float4 a1 = xap[lane + 64];

    float sa = a0.x*a0.x + a0.y*a0.y + a0.z*a0.z + a0.w*a0.w
             + a1.x*a1.x + a1.y*a1.y + a1.z*a1.z + a1.w*a1.w;
    #pragma unroll
    for (int off = 32; off; off >>= 1) sa += __shfl_xor(sa, off);
    float inva = 1.0f / sqrtf(sa);
    a0.x *= inva; a0.y *= inva; a0.z *= inva; a0.w *= inva;
    a1.x *= inva; a1.y *= inva; a1.z *= inva; a1.w *= inva;
    float sqa = a0.x*a0.x + a0.y*a0.y + a0.z*a0.z + a0.w*a0.w
              + a1.x*a1.x + a1.y*a1.y + a1.z*a1.z + a1.w*a1.w;
    #pragma unroll
    for (int off = 32; off; off >>= 1) sqa += __shfl_xor(sqa, off);

    for (int j = w; j < NR; j += 4) {
        const float4* xjp = (const float4*)(xk + j * DZ);
        float4 j0 = xjp[lane];
        float4 j1 = xjp[lane + 64];
        float sj = j0.x*j0.x + j0.y*j0.y + j0.z*j0.z + j0.w*j0.w
                 + j1.x*j1.x + j1.y*j1.y + j1.z*j1.z + j1.w*j1.w;
        #pragma unroll
        for (int off = 32; off; off >>= 1) sj += __shfl_xor(sj, off);
        float invj = 1.0f / sqrtf(sj);
        j0.x *= invj; j0.y *= invj; j0.z *= invj; j0.w *= invj;
        j1.x *= invj; j1.y *= invj; j1.z *= invj; j1.w *= invj;

        float sqj = j0.x*j0.x + j0.y*j0.y + j0.z*j0.z + j0.w*j0.w
                  + j1.x*j1.x + j1.y*j1.y + j1.z*j1.z + j1.w*j1.w;
        float dij = a0.x*j0.x + a0.y*j0.y + a0.z*j0.z + a0.w*j0.w
                  + a1.x*j1.x + a1.y*j1.y + a1.z*j1.z + a1.w*j1.w;
        #pragma unroll
        for (int off = 32; off; off >>= 1) {
            sqj += __shfl_xor(sqj, off);
            dij += __shfl_xor(dij, off);
        }
        float d2 = sqa + sqj - 2.0f * dij;
        float d  = sqrtf(fmaxf(d2, 0.0f));
        if (lane == 0) Dm[((size_t)k * NR + a) * NR + j] = d;
    }
}

// ---------------------------------------------------------------------------
// k_fused (R6-verified structure; R8: W fragments loaded DIRECTLY from the
// clean fp32 input W1 as 8 strided scalar loads + inline hi/lo split — the
// SAME f2bf math the transpose kernel used, so output is bit-identical.
// Removes the 12.6 MB W1h/W1l producer->consumer handoff entirely.)
// ---------------------------------------------------------------------------
__global__ __launch_bounds__(1024) void k_fused(
    const float* __restrict__ x, const float* __restrict__ W1,
    const float* __restrict__ b1, const float* __restrict__ Dm,
    float* __restrict__ G, float* __restrict__ cnt)
{
    __shared__ unsigned short xs_h[25 * XSP], xs_l[25 * XSP];   // 26 KB each
    __shared__ float Ct[4][75 * CP];                            // 81.6 KB
    __shared__ float Dm_s[NR * NR];
    __shared__ float red[16][64];
    __shared__ float cred[4];

    int bid = blockIdx.x;
    int k  = bid >> 4;          // task
    int jt = bid & 15;          // j-tile
    int j0 = jt * 64;

    int tid  = threadIdx.x;
    int lane = tid & 63;
    int w    = tid >> 6;        // 0..15
    int g    = w & 3;           // col group (16 cols each)
    int kh   = w >> 2;          // K quarter (kc 4*kh .. 4*kh+3)
    int q    = lane >> 4;
    int ln16 = lane & 15;

    for (int idx = tid; idx < NR * NR; idx += 1024)
        Dm_s[idx] = Dm[(size_t)k * NR * NR + idx];

    // ---- stage x once (bit-identical hi/lo split) ----
    for (int gi = tid; gi < NR * 64; gi += 1024) {
        int row = gi >> 6;
        int c8  = (gi & 63) * 8;
        const float* xp = x + ((size_t)k * NR + row) * DZ + c8;
        float4 v0 = *(const float4*)(xp);
        float4 v1 = *(const float4*)(xp + 4);
        unsigned short h;
        ushort4 ha, hb, la, lb;
        h = f2bf(v0.x); ha.x = h; la.x = f2bf(v0.x - bf2f(h));
        h = f2bf(v0.y); ha.y = h; la.y = f2bf(v0.y - bf2f(h));
        h = f2bf(v0.z); ha.z = h; la.z = f2bf(v0.z - bf2f(h));
        h = f2bf(v0.w); ha.w = h; la.w = f2bf(v0.w - bf2f(h));
        h = f2bf(v1.x); hb.x = h; lb.x = f2bf(v1.x - bf2f(h));
        h = f2bf(v1.y); hb.y = h; lb.y = f2bf(v1.y - bf2f(h));
        h = f2bf(v1.z); hb.z = h; lb.z = f2bf(v1.z - bf2f(h));
        h = f2bf(v1.w); hb.w = h; lb.w = f2bf(v1.w - bf2f(h));
        *(ushort4*)&xs_h[row * XSP + c8]     = ha;
        *(ushort4*)&xs_h[row * XSP + c8 + 4] = hb;
        *(ushort4*)&xs_l[row * XSP + c8]     = la;
        *(ushort4*)&xs_l[row * XSP + c8 + 4] = lb;
    }
    __syncthreads();

    // semihard count (jt==0, waves 0..3 only; verified body)
    if (jt == 0 && tid < 256) {
        float cntv = 0.0f;
        for (int idx = tid; idx < 2000; idx += 256) {
            int a   = idx / 80;
            int rem = idx - a * 80;
            int mi  = rem / 20;
            int nn  = rem - mi * 20;
            int qa = a % 5, mdiv = a / 5;
            int m = mi + (mi >= mdiv);
            int p = qa + 5 * m;
            int ng = nn >> 2, o = nn & 3;
            int n = ng * 5 + o + (o >= qa);
            float tm = Dm_s[a * NR + n] - Dm_s[a * NR + p];
            cntv += ((tm > 0.0f) && (tm <= 0.8f)) ? 1.0f : 0.0f;
        }
        #pragma unroll
        for (int off = 32; off; off >>= 1) cntv += __shfl_xor(cntv, off);
        if (lane == 0) cred[w] = cntv;
    }

    int rowA1 = 16 + ln16;
    if (rowA1 > 24) rowA1 = 24;    // pad lanes duplicate row 24 (rows 25..31 unused)

    // this lane's W1 column walk: col = j0+g*16+ln16, rows k = kh*128 + q*8 + ...
    const float* wcol = W1 + (size_t)(kh * 128 + q * 8) * D2Z + (j0 + g * 16 + ln16);

    for (int c = 0; c < 3; c++) {
        f32x4 acc0 = (f32x4){0.f,0.f,0.f,0.f};
        f32x4 acc1 = (f32x4){0.f,0.f,0.f,0.f};
        const float* wc = wcol + (size_t)c * DZ * D2Z;

        #pragma unroll
        for (int kc2 = 0; kc2 < 4; kc2++) {     // this wave's K quarter
            int kc  = kh * 4 + kc2;
            int kog = kc * 32 + q * 8;
            const float* bp = wc + (size_t)kc2 * 32 * D2Z;
            bf16x8 b_h, b_l;
            #pragma unroll
            for (int i2 = 0; i2 < 8; i2++) {    // 8 strided fp32 loads + split
                float v = bp[(size_t)i2 * D2Z];
                unsigned short hh = f2bf(v);
                b_h[i2] = (short)hh;
                b_l[i2] = (short)f2bf(v - bf2f(hh));
            }
            bf16x8 a0h = *(const bf16x8*)&xs_h[ln16 * XSP + kog];
            bf16x8 a0l = *(const bf16x8*)&xs_l[ln16 * XSP + kog];
            bf16x8 a1h = *(const bf16x8*)&xs_h[rowA1 * XSP + kog];
            bf16x8 a1l = *(const bf16x8*)&xs_l[rowA1 * XSP + kog];
            acc0 = __builtin_amdgcn_mfma_f32_16x16x32_bf16(a0h, b_h, acc0, 0, 0, 0);
            acc0 = __builtin_amdgcn_mfma_f32_16x16x32_bf16(a0h, b_l, acc0, 0, 0, 0);
            acc0 = __builtin_amdgcn_mfma_f32_16x16x32_bf16(a0l, b_h, acc0, 0, 0, 0);
            acc1 = __builtin_amdgcn_mfma_f32_16x16x32_bf16(a1h, b_h, acc1, 0, 0, 0);
            acc1 = __builtin_amdgcn_mfma_f32_16x16x32_bf16(a1h, b_l, acc1, 0, 0, 0);
            acc1 = __builtin_amdgcn_mfma_f32_16x16x32_bf16(a1l, b_h, acc1, 0, 0, 0);
        }

        int col = g * 16 + ln16;
        #pragma unroll
        for (int r = 0; r < 4; r++) {
            int r0 = q * 4 + r;
            Ct[kh][(c * 25 + r0) * CP + col] = acc0[r];
            int r1 = 16 + q * 4 + r;
            if (r1 < 25) Ct[kh][(c * 25 + r1) * CP + col] = acc1[r];
        }
    }
    __syncthreads();

    if (jt == 0 && tid == 0)
        cnt[k] = cred[0] + cred[1] + cred[2] + cred[3];

    // ---- accum: thread = (col j, valid-m index h, a-split ag 4-way) ----
    int j  = tid & 63;
    int h  = (tid >> 6) & 3;
    int ag = tid >> 8;          // 0..3, wave-uniform
    float b1v = b1[j0 + j];

    float a3v[NR];
    #pragma unroll
    for (int i = 0; i < NR; i++)
        a3v[i] = Ct[0][(50 + i) * CP + j] + Ct[1][(50 + i) * CP + j]
               + Ct[2][(50 + i) * CP + j] + Ct[3][(50 + i) * CP + j];

    float acc = 0.0f;
    #define ACC_BODY(a) { \
        const int qa = (a) % 5, mdiv = (a) / 5; \
        int m = h + (h >= mdiv); \
        int p = qa + 5 * m; \
        float a1v = Ct[0][(a) * CP + j] + Ct[1][(a) * CP + j] \
                  + Ct[2][(a) * CP + j] + Ct[3][(a) * CP + j]; \
        float a2v = Ct[0][(25 + p) * CP + j] + Ct[1][(25 + p) * CP + j] \
                  + Ct[2][(25 + p) * CP + j] + Ct[3][(25 + p) * CP + j]; \
        float dap = Dm_s[(a) * NR + p]; \
        float s = a1v + a2v + b1v; \
        _Pragma("unroll") \
        for (int ng = 0; ng < 5; ng++) { \
            _Pragma("unroll") \
            for (int o = 0; o < 4; o++) { \
                int n = ng * 5 + o + (o >= qa); \
                float tm = Dm_s[(a) * NR + n] - dap; \
                bool sel = (tm > 0.0f) && (tm <= 0.8f); \
                float pre = fmaxf(s + a3v[n], 0.0f); \
                acc = fmaf(sel ? 1.0f : 0.0f, pre, acc); \
            } \
        } }
    if (ag == 0) {
        #pragma unroll
        for (int a = 0; a < 7; a++) ACC_BODY(a)
    } else if (ag == 1) {
        #pragma unroll
        for (int a = 7; a < 13; a++) ACC_BODY(a)
    } else if (ag == 2) {
        #pragma unroll
        for (int a = 13; a < 19; a++) ACC_BODY(a)
    } else {
        #pragma unroll
        for (int a = 19; a < 25; a++) ACC_BODY(a)
    }
    #undef ACC_BODY

    red[tid >> 6][j] = acc;
    __syncthreads();
    if (tid < 64) {
        float s = 0.0f;
        #pragma unroll
        for (int r = 0; r < 16; r++) s += red[r][tid];
        G[(size_t)k * D2Z + j0 + tid] = s;
    }
}

// ---------------------------------------------------------------------------
// Tail (R6/R7-verified): task-batched, 128 blocks each.
// ---------------------------------------------------------------------------

// kA: pooled partials. grid 128 = (jq 0..15) x (ct 0..7), 64-j slices.
__global__ __launch_bounds__(256) void kA(const float* __restrict__ G,
                                          const float* __restrict__ W2,
                                          float* __restrict__ pp)
{
    __shared__ float GsT[64 * 16];      // [jj][t], 4 KB
    __shared__ float red2[4][16][64];   // 16 KB
    int jq = blockIdx.x & 15, ct = blockIdx.x >> 4;
    int tid = threadIdx.x;

    for (int idx = tid; idx < 1024; idx += 256) {
        int t = idx & 15, jj = idx >> 4;
        GsT[jj * 16 + t] = G[(size_t)t * D2Z + jq * 64 + jj];
    }
    __syncthreads();

    int cg = tid & 63, sub = tid >> 6;
    int col = ct * 64 + cg;
    float acc[16];
    #pragma unroll
    for (int t = 0; t < 16; t++) acc[t] = 0.0f;

    for (int jj = 0; jj < 16; jj++) {
        int jr = sub * 16 + jj;
        float wv = W2[(size_t)(jq * 64 + jr) * DZ + col];
        const float4* gp = (const float4*)&GsT[jr * 16];
        float4 g0 = gp[0], g1 = gp[1], g2 = gp[2], g3 = gp[3];
        acc[0]  = fmaf(g0.x, wv, acc[0]);  acc[1]  = fmaf(g0.y, wv, acc[1]);
        acc[2]  = fmaf(g0.z, wv, acc[2]);  acc[3]  = fmaf(g0.w, wv, acc[3]);
        acc[4]  = fmaf(g1.x, wv, acc[4]);  acc[5]  = fmaf(g1.y, wv, acc[5]);
        acc[6]  = fmaf(g1.z, wv, acc[6]);  acc[7]  = fmaf(g1.w, wv, acc[7]);
        acc[8]  = fmaf(g2.x, wv, acc[8]);  acc[9]  = fmaf(g2.y, wv, acc[9]);
        acc[10] = fmaf(g2.z, wv, acc[10]); acc[11] = fmaf(g2.w, wv, acc[11]);
        acc[12] = fmaf(g3.x, wv, acc[12]); acc[13] = fmaf(g3.y, wv, acc[13]);
        acc[14] = fmaf(g3.z, wv, acc[14]); acc[15] = fmaf(g3.w, wv, acc[15]);
    }
    #pragma unroll
    for (int t = 0; t < 16; t++) red2[sub][t][cg] = acc[t];
    __syncthreads();
    for (int r = 0; r < 4; r++) {
        int oi = tid + r * 256;
        int t = oi >> 6, c2 = oi & 63;
        float s = red2[0][t][c2] + red2[1][t][c2] + red2[2][t][c2] + red2[3][t][c2];
        pp[(size_t)jq * 8192 + t * DZ + ct * 64 + c2] = s;
    }
}

// kB: pooled finish (16 slices + cnt*b2) then u partials.
// grid 128 = (ct 0..15) x (cq 0..7), 64-c slices.
__global__ __launch_bounds__(256) void kB(const float* __restrict__ pp,
                                          const float* __restrict__ cnt,
                                          const float* __restrict__ b2,
                                          const float* __restrict__ W3,
                                          float* __restrict__ up)
{
    __shared__ float PsT[64 * 16];      // [cl][t], 4 KB
    __shared__ float red2[4][16][64];
    int ct = blockIdx.x & 15, cq = blockIdx.x >> 4;
    int tid = threadIdx.x;

    for (int idx = tid; idx < 1024; idx += 256) {
        int t = idx & 15, cl = idx >> 4;
        int c = cq * 64 + cl;
        float v = cnt[t] * b2[c];
        #pragma unroll
        for (int sl = 0; sl < 16; sl++)
            v += pp[(size_t)sl * 8192 + t * DZ + c];
        PsT[cl * 16 + t] = v;
    }
    __syncthreads();

    int cg = tid & 63, sub = tid >> 6;
    int col = ct * 64 + cg;
    float acc[16];
    #pragma unroll
    for (int t = 0; t < 16; t++) acc[t] = 0.0f;

    for (int cl = 0; cl < 16; cl++) {
        int cr = sub * 16 + cl;
        float wv = W3[(size_t)(cq * 64 + cr) * D2Z + col];
        const float4* gp = (const float4*)&PsT[cr * 16];
        float4 g0 = gp[0], g1 = gp[1], g2 = gp[2], g3 = gp[3];
        acc[0]  = fmaf(g0.x, wv, acc[0]);  acc[1]  = fmaf(g0.y, wv, acc[1]);
        acc[2]  = fmaf(g0.z, wv, acc[2]);  acc[3]  = fmaf(g0.w, wv, acc[3]);
        acc[4]  = fmaf(g1.x, wv, acc[4]);  acc[5]  = fmaf(g1.y, wv, acc[5]);
        acc[6]  = fmaf(g1.z, wv, acc[6]);  acc[7]  = fmaf(g1.w, wv, acc[7]);
        acc[8]  = fmaf(g2.x, wv, acc[8]);  acc[9]  = fmaf(g2.y, wv, acc[9]);
        acc[10] = fmaf(g2.z, wv, acc[10]); acc[11] = fmaf(g2.w, wv, acc[11]);
        acc[12] = fmaf(g3.x, wv, acc[12]); acc[13] = fmaf(g3.y, wv, acc[13]);
        acc[14] = fmaf(g3.z, wv, acc[14]); acc[15] = fmaf(g3.w, wv, acc[15]);
    }
    #pragma unroll
    for (int t = 0; t < 16; t++) red2[sub][t][cg] = acc[t];
    __syncthreads();
    for (int r = 0; r < 4; r++) {
        int oi = tid + r * 256;
        int t = oi >> 6, c2 = oi & 63;
        float s = red2[0][t][c2] + red2[1][t][c2] + red2[2][t][c2] + red2[3][t][c2];
        up[(size_t)cq * 16384 + t * D2Z + ct * 64 + c2] = s;
    }
}

// kC: u finish (8 slices + b3, relu) then o partials.
// grid 128 = (ct 0..7) x (sq 0..15), 64-s slices.
__global__ __launch_bounds__(256) void kC(const float* __restrict__ up,
                                          const float* __restrict__ b3,
                                          const float* __restrict__ W4,
                                          float* __restrict__ op)
{
    __shared__ float UsT[64 * 16];      // [sl][t], 4 KB
    __shared__ float red2[4][16][64];
    int ct = blockIdx.x & 7, sq = blockIdx.x >> 3;
    int tid = threadIdx.x;

    for (int idx = tid; idx < 1024; idx += 256) {
        int t = idx & 15, sl = idx >> 4;
        int s = sq * 64 + sl;
        float v = b3[s];
        #pragma unroll
        for (int c8 = 0; c8 < 8; c8++)
            v += up[(size_t)c8 * 16384 + t * D2Z + s];
        UsT[sl * 16 + t] = fmaxf(v, 0.0f);
    }
    __syncthreads();

    int cg = tid & 63, sub = tid >> 6;
    int col = ct * 64 + cg;
    float acc[16];
    #pragma unroll
    for (int t = 0; t < 16; t++) acc[t] = 0.0f;

    for (int sl = 0; sl < 16; sl++) {
        int sr = sub * 16 + sl;
        float wv = W4[(size_t)(sq * 64 + sr) * DZ + col];
        const float4* gp = (const float4*)&UsT[sr * 16];
        float4 g0 = gp[0], g1 = gp[1], g2 = gp[2], g3 = gp[3];
        acc[0]  = fmaf(g0.x, wv, acc[0]);  acc[1]  = fmaf(g0.y, wv, acc[1]);
        acc[2]  = fmaf(g0.z, wv, acc[2]);  acc[3]  = fmaf(g0.w, wv, acc[3]);
        acc[4]  = fmaf(g1.x, wv, acc[4]);  acc[5]  = fmaf(g1.y, wv, acc[5]);
        acc[6]  = fmaf(g1.z, wv, acc[6]);  acc[7]  = fmaf(g1.w, wv, acc[7]);
        acc[8]  = fmaf(g2.x, wv, acc[8]);  acc[9]  = fmaf(g2.y, wv, acc[9]);
        acc[10] = fmaf(g2.z, wv, acc[10]); acc[11] = fmaf(g2.w, wv, acc[11]);
        acc[12] = fmaf(g3.x, wv, acc[12]); acc[13] = fmaf(g3.y, wv, acc[13]);
        acc[14] = fmaf(g3.z, wv, acc[14]); acc[15] = fmaf(g3.w, wv, acc[15]);
    }
    #pragma unroll
    for (int t = 0; t < 16; t++) red2[sub][t][cg] = acc[t];
    __syncthreads();
    for (int r = 0; r < 4; r++) {
        int oi = tid + r * 256;
        int t = oi >> 6, c2 = oi & 63;
        float s = red2[0][t][c2] + red2[1][t][c2] + red2[2][t][c2] + red2[3][t][c2];
        op[(size_t)sq * 8192 + t * DZ + ct * 64 + c2] = s;
    }
}

// kD: o finish (16 slices + b4), score, softmax. grid 16 (one per task).
__global__ __launch_bounds__(256) void kD(const float* __restrict__ op,
                                          const float* __restrict__ b4,
                                          const float* __restrict__ Wc,
                                          const float* __restrict__ bc,
                                          float* __restrict__ out)
{
    __shared__ float Os[DZ];
    __shared__ float tmp[4][64];
    int k = blockIdx.x;
    int tid = threadIdx.x;

    for (int c = tid; c < DZ; c += 256) {
        float v = b4[c];
        #pragma unroll
        for (int sl = 0; sl < 16; sl++)
            v += op[(size_t)sl * 8192 + k * DZ + c];
        Os[c] = v;
    }
    __syncthreads();

    int oc = tid & 63, seg = tid >> 6;
    float a0 = 0.f, a1 = 0.f, a2 = 0.f, a3 = 0.f;
    int r0 = seg * 128;
    #pragma unroll 4
    for (int rr = r0; rr < r0 + 128; rr += 4) {
        a0 = fmaf(Os[rr+0], Wc[(size_t)(rr+0) * NC + oc], a0);
        a1 = fmaf(Os[rr+1], Wc[(size_t)(rr+1) * NC + oc], a1);
        a2 = fmaf(Os[rr+2], Wc[(size_t)(rr+2) * NC + oc], a2);
        a3 = fmaf(Os[rr+3], Wc[(size_t)(rr+3) * NC + oc], a3);
    }
    tmp[seg][oc] = (a0 + a1) + (a2 + a3);
    __syncthreads();
    if (tid < 64) {
        float sc = bc[tid] + tmp[0][tid] + tmp[1][tid] + tmp[2][tid] + tmp[3][tid];
        float m = sc;
        #pragma unroll
        for (int off = 32; off; off >>= 1) m = fmaxf(m, __shfl_xor(m, off));
        float e = expf(sc - m);
        float ss = e;
        #pragma unroll
        for (int off = 32; off; off >>= 1) ss += __shfl_xor(ss, off);
        out[k * NC + tid] = e / ss;
    }
}

extern "C" void kernel_launch(void* const* d_in, const int* in_sizes, int n_in,
                              void* d_out, int out_size, void* d_ws, size_t ws_size,
                              hipStream_t stream)
{
    const float* x  = (const float*)d_in[0];
    const float* W1 = (const float*)d_in[1];
    const float* b1 = (const float*)d_in[2];
    const float* W2 = (const float*)d_in[3];
    const float* b2 = (const float*)d_in[4];
    const float* W3 = (const float*)d_in[5];
    const float* b3 = (const float*)d_in[6];
    const float* W4 = (const float*)d_in[7];
    const float* b4 = (const float*)d_in[8];
    const float* Wc = (const float*)d_in[9];
    const float* bc = (const float*)d_in[10];
    float* out = (float*)d_out;

    float* ws   = (float*)d_ws;
    float* Dm   = ws;                         // 10000
    float* cnt  = ws + 10016;                 // 16
    float* G    = ws + 10032;                 // 16384 -> end 26416
    float* pp   = ws + 26416;                 // 16*16*512  = 131072 -> 157488
    float* up   = ws + 157488;                // 8*16*1024  = 131072 -> 288560
    float* op   = ws + 288560;                // 16*16*512  = 131072 -> 419632

    k_dist <<<400,  256, 0, stream>>>(x, Dm);
    k_fused<<<256, 1024, 0, stream>>>(x, W1, b1, Dm, G, cnt);
    kA     <<<128,  256, 0, stream>>>(G, W2, pp);
    kB     <<<128,  256, 0, stream>>>(pp, cnt, b2, W3, up);
    kC     <<<128,  256, 0, stream>>>(up, b3, W4, op);
    kD     <<<NT,   256, 0, stream>>>(op, b4, Wc, bc, out);
}